// Round 2
// baseline (281.508 us; speedup 1.0000x reference)
//
#include <hip/hip_runtime.h>

// BCE loss reduction over (64,8,65536,1) fp32 pred/true.
// loss = -sum(t*max(log p,-100) + (1-t)*max(log(1-p),-100)) / (H*B)
//
// R1 post-mortem: VGPR=20 -> only 2 loads in flight per wave -> latency-bound
// at ~4 B/cyc/CU. Fix: 4x manual unroll, 8 loads issued before first use,
// 4 independent accumulators. Target <=64 VGPR to keep 8 waves/SIMD.

#define LOG_CLAMP -100.0f

__device__ __forceinline__ float bce4(float4 p, float4 t) {
    // For p in [0.5,1], 1-p is exact (Sterbenz); for small p the (1-t)*log(1-p)
    // term is ~0 relative to the ~8.0 result -- well under the 0.16 threshold.
    float r;
    r  = t.x * fmaxf(__logf(p.x), LOG_CLAMP) + (1.0f - t.x) * fmaxf(__logf(1.0f - p.x), LOG_CLAMP);
    r += t.y * fmaxf(__logf(p.y), LOG_CLAMP) + (1.0f - t.y) * fmaxf(__logf(1.0f - p.y), LOG_CLAMP);
    r += t.z * fmaxf(__logf(p.z), LOG_CLAMP) + (1.0f - t.z) * fmaxf(__logf(1.0f - p.z), LOG_CLAMP);
    r += t.w * fmaxf(__logf(p.w), LOG_CLAMP) + (1.0f - t.w) * fmaxf(__logf(1.0f - p.w), LOG_CLAMP);
    return r;
}

__global__ __launch_bounds__(256) void vertical_loss_kernel(
    const float4* __restrict__ p4,
    const float4* __restrict__ t4,
    float* __restrict__ out,
    int n4, float scale)
{
    int tid    = blockIdx.x * blockDim.x + threadIdx.x;
    int stride = gridDim.x * blockDim.x;

    float s0 = 0.0f, s1 = 0.0f, s2 = 0.0f, s3 = 0.0f;

    int i = tid;
    // Unrolled-by-4 main loop: issue all 8 loads before any use so the
    // compiler keeps 8 KB/wave outstanding (vs 2 KB in R1).
    for (; i + 3 * stride < n4; i += 4 * stride) {
        float4 p0 = p4[i];
        float4 p1 = p4[i + stride];
        float4 p2 = p4[i + 2 * stride];
        float4 p3 = p4[i + 3 * stride];
        float4 t0 = t4[i];
        float4 t1 = t4[i + stride];
        float4 t2 = t4[i + 2 * stride];
        float4 t3 = t4[i + 3 * stride];
        s0 += bce4(p0, t0);
        s1 += bce4(p1, t1);
        s2 += bce4(p2, t2);
        s3 += bce4(p3, t3);
    }
    // Tail (not taken for the bench shape: 8,388,608 = 16 * 524,288).
    for (; i < n4; i += stride) {
        s0 += bce4(p4[i], t4[i]);
    }

    float sum = (s0 + s1) + (s2 + s3);

    // wave (64-lane) butterfly reduction
    #pragma unroll
    for (int off = 32; off > 0; off >>= 1)
        sum += __shfl_down(sum, off, 64);

    __shared__ float wsum[4];  // 256 threads = 4 waves
    int wave = threadIdx.x >> 6;
    int lane = threadIdx.x & 63;
    if (lane == 0) wsum[wave] = sum;
    __syncthreads();

    if (threadIdx.x == 0) {
        float s = wsum[0] + wsum[1] + wsum[2] + wsum[3];
        atomicAdd(out, -s * scale);  // device-scope by default on CDNA
    }
}

extern "C" void kernel_launch(void* const* d_in, const int* in_sizes, int n_in,
                              void* d_out, int out_size, void* d_ws, size_t ws_size,
                              hipStream_t stream) {
    const float4* pred  = (const float4*)d_in[0];
    const float4* true_ = (const float4*)d_in[1];
    float* out = (float*)d_out;

    int n  = in_sizes[0];   // 33,554,432
    int n4 = n / 4;         // 8,388,608 float4s
    // Normalization: mean over H (65536), sum over b,c, divide by B (64)
    float scale = 1.0f / (65536.0f * 64.0f);

    // Harness re-poisons d_out with 0xAA before every launch — zero it.
    hipMemsetAsync(d_out, 0, sizeof(float), stream);

    // 2048 blocks x 4 waves = 8192 waves -> 32 waves/CU, 4 unrolled outer
    // iterations per thread (16 logical).
    int blocks = 2048;
    vertical_loss_kernel<<<blocks, 256, 0, stream>>>(pred, true_, out, n4, scale);
}

// Round 3
// 278.416 us; speedup vs baseline: 1.0111x; 1.0111x over previous
//
#include <hip/hip_runtime.h>

// BCE loss reduction over (64,8,65536,1) fp32 pred/true.
// loss = -sum(t*max(log p,-100) + (1-t)*max(log(1-p),-100)) / (65536*64)
//
// Work in log2 domain: max(log x, -100) = ln2 * max(log2 x, -100/ln2).
// bce_elem (log2 units) = lq + t*(lp - lq); final scale folds -ln2/4194304.
//
// R2 post-mortem: compiler sank loads next to uses (VGPR=28) -> 2 KB/wave
// in flight -> 2.5 TB/s read. Fix: software-pipelined prefetch fenced with
// sched_barrier(0) so 8 KB/wave stays outstanding during compute.

#define LOG2_CLAMP -144.26950408889634f   // -100 / ln(2)

__device__ __forceinline__ void bce4_acc(const float4& p, const float4& t,
                                         float& sq, float& sd) {
    float lp, lq;
    lp = fmaxf(__log2f(p.x), LOG2_CLAMP);
    lq = fmaxf(__log2f(1.0f - p.x), LOG2_CLAMP);   // 1-p exact for p>=0.5
    sq += lq; sd = __builtin_fmaf(t.x, lp - lq, sd);
    lp = fmaxf(__log2f(p.y), LOG2_CLAMP);
    lq = fmaxf(__log2f(1.0f - p.y), LOG2_CLAMP);
    sq += lq; sd = __builtin_fmaf(t.y, lp - lq, sd);
    lp = fmaxf(__log2f(p.z), LOG2_CLAMP);
    lq = fmaxf(__log2f(1.0f - p.z), LOG2_CLAMP);
    sq += lq; sd = __builtin_fmaf(t.z, lp - lq, sd);
    lp = fmaxf(__log2f(p.w), LOG2_CLAMP);
    lq = fmaxf(__log2f(1.0f - p.w), LOG2_CLAMP);
    sq += lq; sd = __builtin_fmaf(t.w, lp - lq, sd);
}

__global__ __launch_bounds__(256) void vertical_loss_kernel(
    const float4* __restrict__ p4,
    const float4* __restrict__ t4,
    float* __restrict__ out,
    int n4, float final_scale)
{
    float sq = 0.0f, sd = 0.0f;

    const int chunk = n4 / (int)gridDim.x;           // float4s per block
    const int steps = chunk / (int)blockDim.x;       // iterations per thread

    if ((chunk % (int)blockDim.x) == 0 && (steps & 3) == 0 && steps >= 8) {
        // Block-contiguous tiles, 4x-unrolled, software-pipelined.
        const int stp = (int)blockDim.x;             // 256
        int i = (int)blockIdx.x * chunk + (int)threadIdx.x;

        float4 P0 = p4[i], P1 = p4[i + stp], P2 = p4[i + 2 * stp], P3 = p4[i + 3 * stp];
        float4 T0 = t4[i], T1 = t4[i + stp], T2 = t4[i + 2 * stp], T3 = t4[i + 3 * stp];

        const int groups = steps >> 2;               // 4 for bench shape
        for (int g = 1; g < groups; ++g) {
            i += 4 * stp;
            // Fence: loads may not sink below, compute may not hoist above.
            __builtin_amdgcn_sched_barrier(0);
            float4 Q0 = p4[i], Q1 = p4[i + stp], Q2 = p4[i + 2 * stp], Q3 = p4[i + 3 * stp];
            float4 U0 = t4[i], U1 = t4[i + stp], U2 = t4[i + 2 * stp], U3 = t4[i + 3 * stp];
            __builtin_amdgcn_sched_barrier(0);
            bce4_acc(P0, T0, sq, sd);
            bce4_acc(P1, T1, sq, sd);
            bce4_acc(P2, T2, sq, sd);
            bce4_acc(P3, T3, sq, sd);
            P0 = Q0; P1 = Q1; P2 = Q2; P3 = Q3;
            T0 = U0; T1 = U1; T2 = U2; T3 = U3;
        }
        bce4_acc(P0, T0, sq, sd);
        bce4_acc(P1, T1, sq, sd);
        bce4_acc(P2, T2, sq, sd);
        bce4_acc(P3, T3, sq, sd);
    } else {
        // Generic fallback (not taken for the bench shape).
        for (int i = (int)blockIdx.x * (int)blockDim.x + (int)threadIdx.x;
             i < n4; i += (int)gridDim.x * (int)blockDim.x)
            bce4_acc(p4[i], t4[i], sq, sd);
    }

    float sum = sq + sd;

    // wave (64-lane) reduction
    #pragma unroll
    for (int off = 32; off > 0; off >>= 1)
        sum += __shfl_down(sum, off, 64);

    __shared__ float wsum[4];  // 256 threads = 4 waves
    int wave = threadIdx.x >> 6;
    int lane = threadIdx.x & 63;
    if (lane == 0) wsum[wave] = sum;
    __syncthreads();

    if (threadIdx.x == 0) {
        float s = wsum[0] + wsum[1] + wsum[2] + wsum[3];
        atomicAdd(out, s * final_scale);  // device-scope by default on CDNA
    }
}

extern "C" void kernel_launch(void* const* d_in, const int* in_sizes, int n_in,
                              void* d_out, int out_size, void* d_ws, size_t ws_size,
                              hipStream_t stream) {
    const float4* pred  = (const float4*)d_in[0];
    const float4* true_ = (const float4*)d_in[1];
    float* out = (float*)d_out;

    int n  = in_sizes[0];   // 33,554,432
    int n4 = n / 4;         // 8,388,608 float4s
    // loss = -ln2 * (sq+sd)_total / (65536*64)
    float final_scale = -0.69314718055994531f / (65536.0f * 64.0f);

    // Harness re-poisons d_out with 0xAA before every launch — zero it.
    hipMemsetAsync(d_out, 0, sizeof(float), stream);

    // 2048 blocks x 256 threads: per block a contiguous 4096-float4 chunk,
    // 16 iterations/thread = 4 pipelined groups of 4.
    int blocks = 2048;
    vertical_loss_kernel<<<blocks, 256, 0, stream>>>(pred, true_, out, n4, final_scale);
}